// Round 3
// baseline (24077.351 us; speedup 1.0000x reference)
//
#include <hip/hip_runtime.h>
#include <hip/hip_cooperative_groups.h>
#include <stdint.h>

#define NE 8192
#define NI 2048
#define NN 10240
#define BB 16
#define TT 100
#define NW 320          // u32 words per bitT row (NN/32)
#define AREC_U32 (640 * 64 * 64)  // tiles x kgroups x lanes
#define BREC_U32 (640 * 16 * 64)

#define EXP_SYN_C 0.6065306597126334f
#define DT_SYN_C 0.5f
#define EXP_NMDA_C 0.951229424500714f
#define EXP_TAU_C 0.6065306597126334f
#define DT_TAU_C 0.5f
#define USE_C 0.03f
#define SQRTK 22.62741699796952f
#define C_EI (-1.5f / SQRTK)
#define C_IE (1.0f / SQRTK)
#define C_II (-1.0f / SQRTK)
#define C_STP (1.0f / 512.0f)

typedef float floatx4 __attribute__((ext_vector_type(4)));
typedef __bf16 bf16x8 __attribute__((ext_vector_type(8)));

typedef unsigned int u32_g __attribute__((address_space(1)));
typedef unsigned int u32_l __attribute__((address_space(3)));

__device__ __forceinline__ void gld_lds16(const void* g, void* l) {
    __builtin_amdgcn_global_load_lds((const u32_g*)g, (u32_l*)l, 16, 0, 0);
}

// ---------- pass1: ballot bit-extraction into bitT[m][n-bits] ----------
__global__ __launch_bounds__(256) void ballot_wab(const float* __restrict__ W,
                                                  uint64_t* __restrict__ bitT) {
    int wv = threadIdx.x >> 6, lane = threadIdx.x & 63;
    int m = blockIdx.x * 4 + wv;
    int c0 = (m < NE) ? 128 : 0;
    const float* row = W + (size_t)m * NN;
    for (int c = c0; c < 160; ++c) {
        uint64_t bits = __ballot(row[c * 64 + lane] != 0.0f);
        if (lane == 0) bitT[(size_t)m * 160 + c] = bits;
    }
}

__global__ __launch_bounds__(256) void ballot_stp(const float* __restrict__ W,
                                                  uint64_t* __restrict__ bitT) {
    int wv = threadIdx.x >> 6, lane = threadIdx.x & 63;
    int m = blockIdx.x * 4 + wv;  // 0..NE-1
    const float* row = W + (size_t)m * NE;
    for (int c = 0; c < 128; ++c) {
        uint64_t bits = __ballot(row[c * 64 + lane] != 0.0f);
        if (lane == 0) bitT[(size_t)m * 160 + c] = bits;
    }
}

// ---------- pass2: reorder bits into MFMA-A-fragment records ----------
__global__ __launch_bounds__(256) void build_rec(const uint32_t* __restrict__ bitT32,
                                                 uint32_t* __restrict__ Arec,
                                                 uint32_t* __restrict__ Brec) {
    int tid = blockIdx.x * 256 + threadIdx.x;
    uint32_t* outp;
    int tau, l, mbase;
    if (tid < AREC_U32) {
        l = tid & 63;
        int g = (tid >> 6) & 63;
        tau = tid >> 12;
        mbase = g * 128;
        outp = Arec + tid;
    } else {
        int t2 = tid - AREC_U32;
        l = t2 & 63;
        int g = (t2 >> 6) & 15;
        tau = t2 >> 10;
        mbase = NE + g * 128;
        outp = Brec + t2;
    }
    int n = tau * 16 + (l & 15);
    int quad = l >> 4;
    int word = n >> 5, bit = n & 31;
    uint32_t out = 0;
    for (int s = 0; s < 4; ++s) {
        int mb = mbase + s * 32 + quad * 8;
        uint32_t byte = 0;
        #pragma unroll
        for (int j = 0; j < 8; ++j) {
            uint32_t w = bitT32[(size_t)(mb + j) * NW + word];
            byte |= ((w >> bit) & 1u) << j;
        }
        out |= byte << (s * 8);
    }
    *outp = out;
}

__device__ __forceinline__ uint32_t bf16rtn(float xf) {
    uint32_t v = __float_as_uint(xf);
    return (v + 0x7FFFu + ((v >> 16) & 1u)) >> 16;
}

// fragment slot for value (batch b, neuron-as-k index n):
// ushort index = kstep*512 + (quad*16 + b)*8 + j ; kstep=n>>5, quad=(n>>3)&3, j=n&7
__device__ __forceinline__ int fidx(int b, int n) {
    return ((n >> 5) << 9) + ((((n >> 3) & 3) * 16 + b) << 3) + (n & 7);
}

// ---------- init: state in [b][n] layout + initial bf16 fragments ----------
__global__ void init_state(const float* __restrict__ ff, const float* __restrict__ rec_in,
                           float* __restrict__ rates0, float* __restrict__ rec0,
                           float* __restrict__ rec1, float* __restrict__ u,
                           float* __restrict__ x, ushort* __restrict__ Fr0,
                           ushort* __restrict__ Fa0) {
    int tid = blockIdx.x * blockDim.x + threadIdx.x;
    if (tid >= BB * NN) return;
    int b = tid / NN, n = tid - b * NN;
    float r0c = rec_in[tid];
    float r1c = rec_in[BB * NN + tid];
    float f = ff[(size_t)b * TT * NN + n];
    float r = (f + r0c) - 1.0f;
    r = r > 0.0f ? r : 0.0f;
    rates0[tid] = r;
    rec0[tid] = r0c;
    rec1[tid] = r1c;
    Fr0[fidx(b, n)] = (ushort)bf16rtn(r);
    if (n < NE) {
        int o2 = b * NE + n;
        float uu = USE_C;
        uu = uu + 0.01f * (USE_C - uu) + USE_C * (1.0f - uu) * r * 0.01f;
        float xx = 1.0f;
        xx = xx + 0.01f * (1.0f - xx) * 4.0f - uu * xx * r * 0.01f;
        u[o2] = uu;
        x[o2] = xx;
        Fa0[fidx(b, n)] = (ushort)bf16rtn(uu * xx * r);
    }
}

// VALU mask-byte -> bf16x8 {0,1.0} expansion (no LDS, no LUT).
__device__ __forceinline__ bf16x8 expand8(uint32_t a32, int s) {
    uint32_t lo = (a32 >> (8 * s)) & 15u;
    uint32_t hi = (a32 >> (8 * s + 4)) & 15u;
    uint32_t sl = (lo * 0x208041u) & 0x01010101u;
    uint32_t sh = (hi * 0x208041u) & 0x01010101u;
    union {
        uint32_t u[4];
        bf16x8 v;
    } af;
    af.u[0] = (sl & 0x10001u) * 0x3F80u;
    af.u[1] = ((sl >> 8) & 0x10001u) * 0x3F80u;
    af.u[2] = (sh & 0x10001u) * 0x3F80u;
    af.u[3] = ((sh >> 8) & 0x10001u) * 0x3F80u;
    return af.v;
}

// ================= persistent cooperative kernel: all 100 steps =================
// grid = 800 = 40 taugroups x 20 k-slices; block = 256 thr = 4 waves.
// Block (tg, sl): 16 taus (tau = tg*16 + w*4 + ta), k-slice of 16 ksteps (512 K).
//   sl<16 : E-pres slice, Arec g [sl*4, sl*4+4), frags = (tg<32 ? Fa : Fr) E-range
//   sl>=16: I-pres slice, Brec g [(sl-16)*4, +4), frags = Fr I-range
// hp[20][b][n]: sA = sum sl<16, sB = sum sl>=16.
// Phase U: element e = bid*256+tid < BB*NN (blocks 640..799 idle in U).
__global__ __launch_bounds__(256, 4) void net_run(
    const float* __restrict__ ff, const uint32_t* __restrict__ Arec,
    const uint32_t* __restrict__ Brec, ushort* __restrict__ Fr,
    ushort* __restrict__ Fa, float* __restrict__ hp, float* __restrict__ rates,
    float* __restrict__ u, float* __restrict__ x, float* __restrict__ rec0,
    float* __restrict__ rec1, float* __restrict__ out) {
    cooperative_groups::grid_group grid = cooperative_groups::this_grid();
    __shared__ ushort bfrag[8192];       // 16 KB: 16 ksteps x 64 lanes x 8 bf16
    __shared__ float tt[4][4][16][20];   // 20 KB: per-wave transpose tiles [b][n+pad]
    const int tid = threadIdx.x, bid = blockIdx.x;
    const int tg = bid / 20, sl = bid % 20;
    const int w = tid >> 6, lane = tid & 63;
    const int tau0 = tg * 16 + w * 4;
    const uint32_t* recbase;
    const ushort* fsrc;
    int gpt;
    if (sl < 16) {
        recbase = Arec;
        gpt = 64;
        fsrc = (tg < 32 ? Fa : Fr) + sl * (16 * 512);
    } else {
        recbase = Brec;
        gpt = 16;
        fsrc = Fr + (256 + (sl - 16) * 16) * 512;
    }
    const int g0 = (sl < 16 ? sl : sl - 16) * 4;
    float* hpsl = hp + (size_t)sl * (BB * NN);
    // update-phase element
    const int e = bid * 256 + tid;
    const int ub = e / NN, un = e - ub * NN;
    const bool do_u = (e < BB * NN);
    const float* ffrow = ff + (size_t)ub * TT * NN + un;
    float* outrow = out + (size_t)ub * TT * NN + un;

    for (int t = 0; t < TT; ++t) {
        // ---------------- phase G ----------------
        {
            const char* gsrc = (const char*)fsrc + tid * 16;
            char* l = (char*)bfrag + tid * 16;
            #pragma unroll
            for (int i = 0; i < 4; ++i) gld_lds16(gsrc + i * 4096, l + i * 4096);
        }
        uint32_t a[4][4];
        #pragma unroll
        for (int ta = 0; ta < 4; ++ta) {
            const uint32_t* rp = recbase + ((size_t)(tau0 + ta) * gpt + g0) * 64 + lane;
            #pragma unroll
            for (int gg = 0; gg < 4; ++gg) a[ta][gg] = rp[gg * 64];
        }
        floatx4 acc[4];
        #pragma unroll
        for (int ta = 0; ta < 4; ++ta) acc[ta] = (floatx4){0.f, 0.f, 0.f, 0.f};
        __syncthreads();  // drains vmcnt -> LDS staged
        #pragma unroll
        for (int ks = 0; ks < 16; ++ks) {
            bf16x8 bf = *(const bf16x8*)&bfrag[ks * 512 + lane * 8];
            int gg = ks >> 2, s = ks & 3;
            #pragma unroll
            for (int ta = 0; ta < 4; ++ta)
                acc[ta] = __builtin_amdgcn_mfma_f32_16x16x32_bf16(expand8(a[ta][gg], s),
                                                                  bf, acc[ta], 0, 0, 0);
        }
        // epilogue: per-wave LDS transpose -> line-coalesced hp stores
        #pragma unroll
        for (int ta = 0; ta < 4; ++ta)
            *reinterpret_cast<floatx4*>(&tt[w][ta][lane & 15][(lane >> 4) * 4]) = acc[ta];
        #pragma unroll
        for (int ta = 0; ta < 4; ++ta) {
            floatx4 v = *reinterpret_cast<const floatx4*>(
                &tt[w][ta][lane >> 2][(lane & 3) * 4]);
            int nb = (tau0 + ta) * 16 + (lane & 3) * 4;
            *reinterpret_cast<floatx4*>(&hpsl[(size_t)(lane >> 2) * NN + nb]) = v;
        }
        grid.sync();
        // ---------------- phase U ----------------
        if (do_u) {
            float sA = 0.f, sB = 0.f;
            #pragma unroll
            for (int p = 0; p < 16; ++p) sA += hp[(size_t)p * (BB * NN) + e];
            #pragma unroll
            for (int p = 16; p < 20; ++p) sB += hp[(size_t)p * (BB * NN) + e];
            float hidden, hidden2;
            if (un < NE) {
                float h_stp = C_STP * sA;
                hidden = C_EI * sB + h_stp;
                hidden2 = h_stp;
            } else {
                hidden = C_IE * sA + C_II * sB;
                hidden2 = C_IE * sA;
            }
            float r0 = rec0[e] * EXP_SYN_C + hidden * DT_SYN_C;
            float r1 = rec1[e] * EXP_NMDA_C + 0.4f * hidden2 * 0.05f;
            float fv = ffrow[(size_t)t * NN];
            float net = (fv + r0) + r1;
            float nl = net - 1.0f;
            nl = nl > 0.0f ? nl : 0.0f;
            float rnew = rates[e] * EXP_TAU_C + nl * DT_TAU_C;
            rec0[e] = r0;
            rec1[e] = r1;
            rates[e] = rnew;
            outrow[(size_t)t * NN] = rnew;
            Fr[fidx(ub, un)] = (ushort)bf16rtn(rnew);
            if (un < NE) {
                int o2 = ub * NE + un;
                float uu = u[o2];
                uu = uu + 0.01f * (USE_C - uu) + USE_C * (1.0f - uu) * rnew * 0.01f;
                float xx = x[o2];
                xx = xx + 0.01f * (1.0f - xx) * 4.0f - uu * xx * rnew * 0.01f;
                u[o2] = uu;
                x[o2] = xx;
                Fa[fidx(ub, un)] = (ushort)bf16rtn(uu * xx * rnew);
            }
        }
        grid.sync();
    }
}

// ================= fallback (verified 2-kernel path) =================
__global__ __launch_bounds__(256) void gemm_step(const ushort* __restrict__ Fr,
                                                 const ushort* __restrict__ Fa,
                                                 const uint32_t* __restrict__ Arec,
                                                 const uint32_t* __restrict__ Brec,
                                                 float* __restrict__ hp) {
    __shared__ ushort bfrag[16384];
    const int tid = threadIdx.x;
    const int bid = blockIdx.x;
    int mg, slice, part, recPerTile;
    const uint32_t* rec;
    const ushort* fsrc;
    if (bid < 640) {
        mg = bid >> 3;
        slice = bid & 7;
        part = slice;
        rec = Arec;
        recPerTile = 64;
        fsrc = (mg < 64 ? Fa : Fr) + slice * (32 * 512);
    } else {
        int b2 = bid - 640;
        mg = b2 >> 1;
        slice = b2 & 1;
        part = 8 + slice;
        rec = Brec;
        recPerTile = 16;
        fsrc = Fr + (256 + slice * 32) * 512;
    }
    {
        const char* g = (const char*)fsrc + tid * 16;
        char* l = (char*)bfrag + tid * 16;
        #pragma unroll
        for (int i = 0; i < 8; ++i) gld_lds16(g + i * 4096, l + i * 4096);
    }
    const int w = tid >> 6, lane = tid & 63;
    const int tau0 = mg * 8 + w * 2;
    const uint32_t* recw0 = rec + ((size_t)tau0 * recPerTile + slice * 8) * 64 + lane;
    const uint32_t* recw1 = recw0 + recPerTile * 64;
    uint32_t a0[8], a1[8];
    #pragma unroll
    for (int h = 0; h < 8; ++h) {
        a0[h] = recw0[h * 64];
        a1[h] = recw1[h * 64];
    }
    floatx4 acc0 = {0.f, 0.f, 0.f, 0.f};
    floatx4 acc1 = {0.f, 0.f, 0.f, 0.f};
    __syncthreads();
    #pragma unroll
    for (int h = 0; h < 8; ++h) {
        #pragma unroll
        for (int s = 0; s < 4; ++s) {
            bf16x8 bf = *(const bf16x8*)&bfrag[(h * 4 + s) * 512 + lane * 8];
            acc0 = __builtin_amdgcn_mfma_f32_16x16x32_bf16(expand8(a0[h], s), bf, acc0,
                                                           0, 0, 0);
            acc1 = __builtin_amdgcn_mfma_f32_16x16x32_bf16(expand8(a1[h], s), bf, acc1,
                                                           0, 0, 0);
        }
    }
    float* outp = hp + (size_t)part * (BB * NN);
    int bb = lane & 15, r0 = (lane >> 4) * 4;
    int nb0 = tau0 * 16 + r0;
    #pragma unroll
    for (int r = 0; r < 4; ++r) outp[(size_t)bb * NN + nb0 + r] = acc0[r];
    #pragma unroll
    for (int r = 0; r < 4; ++r) outp[(size_t)bb * NN + nb0 + 16 + r] = acc1[r];
}

__global__ __launch_bounds__(256) void update_step(
    const float* __restrict__ ff, int t, const float* __restrict__ hp,
    const float* __restrict__ rates_cur, float* __restrict__ rates_nxt,
    float* __restrict__ u, float* __restrict__ x, ushort* __restrict__ Fr_nxt,
    ushort* __restrict__ Fa_nxt, float* __restrict__ rec0, float* __restrict__ rec1,
    float* __restrict__ out) {
    int tid = blockIdx.x * 256 + threadIdx.x;
    int b = tid / NN, n = tid - b * NN;
    float sA = 0.f, sB = 0.f;
    #pragma unroll
    for (int p = 0; p < 8; ++p) sA += hp[(size_t)p * (BB * NN) + tid];
    sB = hp[(size_t)8 * (BB * NN) + tid] + hp[(size_t)9 * (BB * NN) + tid];
    float hidden, hidden2;
    if (n < NE) {
        float h_stp = C_STP * sA;
        hidden = C_EI * sB + h_stp;
        hidden2 = h_stp;
    } else {
        hidden = C_IE * sA + C_II * sB;
        hidden2 = C_IE * sA;
    }
    float r0 = rec0[tid] * EXP_SYN_C + hidden * DT_SYN_C;
    float r1 = rec1[tid] * EXP_NMDA_C + 0.4f * hidden2 * 0.05f;
    float fv = ff[(size_t)b * TT * NN + (size_t)t * NN + n];
    float net = (fv + r0) + r1;
    float nl = net - 1.0f;
    nl = nl > 0.0f ? nl : 0.0f;
    float rnew = rates_cur[tid] * EXP_TAU_C + nl * DT_TAU_C;
    rec0[tid] = r0;
    rec1[tid] = r1;
    rates_nxt[tid] = rnew;
    out[(size_t)b * TT * NN + (size_t)t * NN + n] = rnew;
    Fr_nxt[fidx(b, n)] = (ushort)bf16rtn(rnew);
    if (n < NE) {
        int o2 = b * NE + n;
        float uu = u[o2];
        uu = uu + 0.01f * (USE_C - uu) + USE_C * (1.0f - uu) * rnew * 0.01f;
        float xx = x[o2];
        xx = xx + 0.01f * (1.0f - xx) * 4.0f - uu * xx * rnew * 0.01f;
        u[o2] = uu;
        x[o2] = xx;
        Fa_nxt[fidx(b, n)] = (ushort)bf16rtn(uu * xx * rnew);
    }
}

extern "C" void kernel_launch(void* const* d_in, const int* in_sizes, int n_in,
                              void* d_out, int out_size, void* d_ws, size_t ws_size,
                              hipStream_t stream) {
    const float* ff = (const float*)d_in[0];      // (B, T, N)
    const float* rec = (const float*)d_in[1];     // (2, B, N)
    const float* Wab_T = (const float*)d_in[2];   // (N, N)
    const float* Wstp_T = (const float*)d_in[3];  // (NE, NE)
    float* out = (float*)d_out;

    char* p = (char*)d_ws;
    auto alloc = [&](size_t bytes) {
        char* r = p;
        p += (bytes + 255) & ~(size_t)255;
        return r;
    };
    uint64_t* bitT = (uint64_t*)alloc((size_t)NN * 160 * 8);      // 13.1 MB
    uint32_t* Arec = (uint32_t*)alloc((size_t)AREC_U32 * 4);      // 10.5 MB
    uint32_t* Brec = (uint32_t*)alloc((size_t)BREC_U32 * 4);      // 2.6 MB
    float* hp = (float*)alloc((size_t)20 * BB * NN * 4);          // 13.1 MB
    float* rates0 = (float*)alloc((size_t)NN * BB * 4);
    float* rates1 = (float*)alloc((size_t)NN * BB * 4);
    float* u = (float*)alloc((size_t)NE * BB * 4);
    float* x = (float*)alloc((size_t)NE * BB * 4);
    float* rec0 = (float*)alloc((size_t)NN * BB * 4);
    float* rec1 = (float*)alloc((size_t)NN * BB * 4);
    ushort* Fr0 = (ushort*)alloc((size_t)320 * 512 * 2);          // 328 KB
    ushort* Fr1 = (ushort*)alloc((size_t)320 * 512 * 2);
    ushort* Fa0 = (ushort*)alloc((size_t)256 * 512 * 2);          // 262 KB
    ushort* Fa1 = (ushort*)alloc((size_t)256 * 512 * 2);

    ballot_wab<<<NN / 4, 256, 0, stream>>>(Wab_T, bitT);
    ballot_stp<<<NE / 4, 256, 0, stream>>>(Wstp_T, bitT);
    build_rec<<<(AREC_U32 + BREC_U32) / 256, 256, 0, stream>>>((const uint32_t*)bitT,
                                                               Arec, Brec);
    init_state<<<(BB * NN + 255) / 256, 256, 0, stream>>>(ff, rec, rates0, rec0, rec1, u,
                                                          x, Fr0, Fa0);
    // ---- preferred: persistent cooperative kernel (1 launch, 100 steps) ----
    void* args[] = {(void*)&ff,  (void*)&Arec, (void*)&Brec, (void*)&Fr0,
                    (void*)&Fa0, (void*)&hp,   (void*)&rates0, (void*)&u,
                    (void*)&x,   (void*)&rec0, (void*)&rec1, (void*)&out};
    hipError_t err = hipLaunchCooperativeKernel((void*)net_run, dim3(800), dim3(256),
                                                args, 0, stream);
    if (err != hipSuccess) {
        (void)hipGetLastError();  // clear; fall back to verified 2-kernel path
        float* rbuf[2] = {rates0, rates1};
        ushort* Frb[2] = {Fr0, Fr1};
        ushort* Fab[2] = {Fa0, Fa1};
        for (int t = 0; t < TT; ++t) {
            gemm_step<<<800, 256, 0, stream>>>(Frb[t & 1], Fab[t & 1], Arec, Brec, hp);
            update_step<<<BB * NN / 256, 256, 0, stream>>>(ff, t, hp, rbuf[t & 1],
                                                           rbuf[(t + 1) & 1], u, x,
                                                           Frb[(t + 1) & 1],
                                                           Fab[(t + 1) & 1], rec0, rec1,
                                                           out);
        }
    }
}

// Round 4
// 2365.724 us; speedup vs baseline: 10.1776x; 10.1776x over previous
//
#include <hip/hip_runtime.h>
#include <stdint.h>

#define NE 8192
#define NI 2048
#define NN 10240
#define BB 16
#define TT 100
#define NW 320          // u32 words per bitT row (NN/32)
#define AREC_U32 (640 * 64 * 64)  // tiles x kgroups x lanes
#define BREC_U32 (640 * 16 * 64)

#define EXP_SYN_C 0.6065306597126334f
#define DT_SYN_C 0.5f
#define EXP_NMDA_C 0.951229424500714f
#define EXP_TAU_C 0.6065306597126334f
#define DT_TAU_C 0.5f
#define USE_C 0.03f
#define SQRTK 22.62741699796952f
#define C_EI (-1.5f / SQRTK)
#define C_IE (1.0f / SQRTK)
#define C_II (-1.0f / SQRTK)
#define C_STP (1.0f / 512.0f)

typedef float floatx4 __attribute__((ext_vector_type(4)));
typedef __bf16 bf16x8 __attribute__((ext_vector_type(8)));

typedef unsigned int u32_g __attribute__((address_space(1)));
typedef unsigned int u32_l __attribute__((address_space(3)));

__device__ __forceinline__ void gld_lds16(const void* g, void* l) {
    __builtin_amdgcn_global_load_lds((const u32_g*)g, (u32_l*)l, 16, 0, 0);
}

// ---------- pass1: ballot bit-extraction into bitT[m][n-bits] ----------
__global__ __launch_bounds__(256) void ballot_wab(const float* __restrict__ W,
                                                  uint64_t* __restrict__ bitT) {
    int wv = threadIdx.x >> 6, lane = threadIdx.x & 63;
    int m = blockIdx.x * 4 + wv;
    int c0 = (m < NE) ? 128 : 0;
    const float* row = W + (size_t)m * NN;
    for (int c = c0; c < 160; ++c) {
        uint64_t bits = __ballot(row[c * 64 + lane] != 0.0f);
        if (lane == 0) bitT[(size_t)m * 160 + c] = bits;
    }
}

__global__ __launch_bounds__(256) void ballot_stp(const float* __restrict__ W,
                                                  uint64_t* __restrict__ bitT) {
    int wv = threadIdx.x >> 6, lane = threadIdx.x & 63;
    int m = blockIdx.x * 4 + wv;  // 0..NE-1
    const float* row = W + (size_t)m * NE;
    for (int c = 0; c < 128; ++c) {
        uint64_t bits = __ballot(row[c * 64 + lane] != 0.0f);
        if (lane == 0) bitT[(size_t)m * 160 + c] = bits;
    }
}

// ---------- pass2: reorder bits into MFMA-A-fragment records ----------
__global__ __launch_bounds__(256) void build_rec(const uint32_t* __restrict__ bitT32,
                                                 uint32_t* __restrict__ Arec,
                                                 uint32_t* __restrict__ Brec) {
    int tid = blockIdx.x * 256 + threadIdx.x;
    uint32_t* outp;
    int tau, l, mbase;
    if (tid < AREC_U32) {
        l = tid & 63;
        int g = (tid >> 6) & 63;
        tau = tid >> 12;
        mbase = g * 128;
        outp = Arec + tid;
    } else {
        int t2 = tid - AREC_U32;
        l = t2 & 63;
        int g = (t2 >> 6) & 15;
        tau = t2 >> 10;
        mbase = NE + g * 128;
        outp = Brec + t2;
    }
    int n = tau * 16 + (l & 15);
    int quad = l >> 4;
    int word = n >> 5, bit = n & 31;
    uint32_t out = 0;
    for (int s = 0; s < 4; ++s) {
        int mb = mbase + s * 32 + quad * 8;
        uint32_t byte = 0;
        #pragma unroll
        for (int j = 0; j < 8; ++j) {
            uint32_t w = bitT32[(size_t)(mb + j) * NW + word];
            byte |= ((w >> bit) & 1u) << j;
        }
        out |= byte << (s * 8);
    }
    *outp = out;
}

__device__ __forceinline__ uint32_t bf16rtn(float xf) {
    uint32_t v = __float_as_uint(xf);
    return (v + 0x7FFFu + ((v >> 16) & 1u)) >> 16;
}

// fragment slot for value (batch b, neuron-as-k index n):
// ushort index = kstep*512 + (quad*16 + b)*8 + j ; kstep=n>>5, quad=(n>>3)&3, j=n&7
__device__ __forceinline__ int fidx(int b, int n) {
    return ((n >> 5) << 9) + ((((n >> 3) & 3) * 16 + b) << 3) + (n & 7);
}

// ---------- init: state in [b][n] layout + initial bf16 fragments ----------
__global__ void init_state(const float* __restrict__ ff, const float* __restrict__ rec_in,
                           float* __restrict__ rates0, float* __restrict__ rec0,
                           float* __restrict__ rec1, float* __restrict__ u,
                           float* __restrict__ x, ushort* __restrict__ Fr0,
                           ushort* __restrict__ Fa0) {
    int tid = blockIdx.x * blockDim.x + threadIdx.x;
    if (tid >= BB * NN) return;
    int b = tid / NN, n = tid - b * NN;
    float r0c = rec_in[tid];
    float r1c = rec_in[BB * NN + tid];
    float f = ff[(size_t)b * TT * NN + n];
    float r = (f + r0c) - 1.0f;
    r = r > 0.0f ? r : 0.0f;
    rates0[tid] = r;
    rec0[tid] = r0c;
    rec1[tid] = r1c;
    Fr0[fidx(b, n)] = (ushort)bf16rtn(r);
    if (n < NE) {
        int o2 = b * NE + n;
        float uu = USE_C;
        uu = uu + 0.01f * (USE_C - uu) + USE_C * (1.0f - uu) * r * 0.01f;
        float xx = 1.0f;
        xx = xx + 0.01f * (1.0f - xx) * 4.0f - uu * xx * r * 0.01f;
        u[o2] = uu;
        x[o2] = xx;
        Fa0[fidx(b, n)] = (ushort)bf16rtn(uu * xx * r);
    }
}

// VALU mask-byte -> bf16x8 {0,1.0} expansion (no LDS, no LUT).
// nib * 0x208041 spreads bits (b0,b2,b1,b3) to byte lanes 0..3 (no carries);
// (x & 0x10001) * 0x3F80 packs two bf16 1.0/0.0 into one u32.
// Verified bit-identical to the LUT path (round-2 harness pass, absmax 0.03125).
__device__ __forceinline__ bf16x8 expand8(uint32_t a32, int s) {
    uint32_t lo = (a32 >> (8 * s)) & 15u;
    uint32_t hi = (a32 >> (8 * s + 4)) & 15u;
    uint32_t sl = (lo * 0x208041u) & 0x01010101u;
    uint32_t sh = (hi * 0x208041u) & 0x01010101u;
    union {
        uint32_t u[4];
        bf16x8 v;
    } af;
    af.u[0] = (sl & 0x10001u) * 0x3F80u;
    af.u[1] = ((sl >> 8) & 0x10001u) * 0x3F80u;
    af.u[2] = (sh & 0x10001u) * 0x3F80u;
    af.u[3] = ((sh >> 8) & 0x10001u) * 0x3F80u;
    return af.v;
}

// ---------- per-step masked GEMM via MFMA ----------
// grid.x = 1600: bid<1280: gemm-A (E-pres), mg=bid/8, slice=bid%8 (K-slice 1024)
//                else:      gemm-B (I-pres), mg, slice in {0,1}
// block = 256 = 4 waves; wave w handles M-tile tau = mg*4+w (16 posts), N=16 batches.
// B operand pre-packed in global (Fr/Fa); staged 32 KB/block via global_load_lds DMA.
// A-mask bytes expanded to bf16 {0,1} in VALU (expand8) -- no LDS LUT gathers.
// Note bid%8 == slice for the A part -> slice s lands on XCD s (L2-local staging).
__global__ __launch_bounds__(256) void gemm_step(const ushort* __restrict__ Fr,
                                                 const ushort* __restrict__ Fa,
                                                 const uint32_t* __restrict__ Arec,
                                                 const uint32_t* __restrict__ Brec,
                                                 float* __restrict__ hp) {
    __shared__ ushort bfrag[16384];  // 32 ksteps x 64 lanes x 8 bf16 = 32 KB
    const int tid = threadIdx.x;
    const int bid = blockIdx.x;
    int mg, slice, part, recPerTile;
    const uint32_t* rec;
    const ushort* fsrc;
    if (bid < 1280) {
        mg = bid >> 3;
        slice = bid & 7;
        part = slice;
        rec = Arec;
        recPerTile = 64;
        fsrc = (mg < 128 ? Fa : Fr) + slice * (32 * 512);
    } else {
        int b2 = bid - 1280;
        mg = b2 >> 1;
        slice = b2 & 1;
        part = 8 + slice;
        rec = Brec;
        recPerTile = 16;
        fsrc = Fr + (256 + slice * 32) * 512;
    }
    // DMA-stage the 32 KB fragment slice (no VGPR round-trip, no conversion)
    {
        const char* g = (const char*)fsrc + tid * 16;
        char* l = (char*)bfrag + tid * 16;
        #pragma unroll
        for (int i = 0; i < 8; ++i) gld_lds16(g + i * 4096, l + i * 4096);
    }
    const int w = tid >> 6, lane = tid & 63;
    const int tau = mg * 4 + w;
    const uint32_t* recw = rec + ((size_t)tau * recPerTile + slice * 8) * 64 + lane;
    // prefetch all A-records to registers while the DMA is in flight
    uint32_t a[8];
    #pragma unroll
    for (int h = 0; h < 8; ++h) a[h] = recw[h * 64];
    floatx4 acc = {0.f, 0.f, 0.f, 0.f};
    __syncthreads();  // compiler drains vmcnt(0) here -> LDS filled
    #pragma unroll
    for (int h = 0; h < 8; ++h) {
        #pragma unroll
        for (int s = 0; s < 4; ++s) {
            bf16x8 bf = *(const bf16x8*)&bfrag[(h * 4 + s) * 512 + lane * 8];
            acc = __builtin_amdgcn_mfma_f32_16x16x32_bf16(expand8(a[h], s), bf, acc,
                                                          0, 0, 0);
        }
    }
    // epilogue: D[row=(lane>>4)*4+r][col=lane&15] -> hp[part][b][n]
    float* outp = hp + (size_t)part * (BB * NN);
    int bb = lane & 15, r0 = (lane >> 4) * 4;
    int nb = tau * 16 + r0;
    #pragma unroll
    for (int r = 0; r < 4; ++r) outp[(size_t)bb * NN + nb + r] = acc[r];
}

// ---------- per-step neuron update (+ bf16 fragment production) ----------
__global__ __launch_bounds__(256) void update_step(
    const float* __restrict__ ff, int t, const float* __restrict__ hp,
    const float* __restrict__ rates_cur, float* __restrict__ rates_nxt,
    float* __restrict__ u, float* __restrict__ x, ushort* __restrict__ Fr_nxt,
    ushort* __restrict__ Fa_nxt, float* __restrict__ rec0, float* __restrict__ rec1,
    float* __restrict__ out) {
    int tid = blockIdx.x * 256 + threadIdx.x;
    int b = tid / NN, n = tid - b * NN;
    float sA = 0.f, sB = 0.f;
    #pragma unroll
    for (int p = 0; p < 8; ++p) sA += hp[(size_t)p * (BB * NN) + tid];
    sB = hp[(size_t)8 * (BB * NN) + tid] + hp[(size_t)9 * (BB * NN) + tid];
    float hidden, hidden2;
    if (n < NE) {
        float h_stp = C_STP * sA;
        hidden = C_EI * sB + h_stp;
        hidden2 = h_stp;
    } else {
        hidden = C_IE * sA + C_II * sB;
        hidden2 = C_IE * sA;
    }
    float r0 = rec0[tid] * EXP_SYN_C + hidden * DT_SYN_C;
    float r1 = rec1[tid] * EXP_NMDA_C + 0.4f * hidden2 * 0.05f;
    float fv = ff[(size_t)b * TT * NN + (size_t)t * NN + n];
    float net = (fv + r0) + r1;
    float nl = net - 1.0f;
    nl = nl > 0.0f ? nl : 0.0f;
    float rnew = rates_cur[tid] * EXP_TAU_C + nl * DT_TAU_C;
    rec0[tid] = r0;
    rec1[tid] = r1;
    rates_nxt[tid] = rnew;
    out[(size_t)b * TT * NN + (size_t)t * NN + n] = rnew;
    Fr_nxt[fidx(b, n)] = (ushort)bf16rtn(rnew);
    if (n < NE) {
        int o2 = b * NE + n;
        float uu = u[o2];
        uu = uu + 0.01f * (USE_C - uu) + USE_C * (1.0f - uu) * rnew * 0.01f;
        float xx = x[o2];
        xx = xx + 0.01f * (1.0f - xx) * 4.0f - uu * xx * rnew * 0.01f;
        u[o2] = uu;
        x[o2] = xx;
        Fa_nxt[fidx(b, n)] = (ushort)bf16rtn(uu * xx * rnew);
    }
}

extern "C" void kernel_launch(void* const* d_in, const int* in_sizes, int n_in,
                              void* d_out, int out_size, void* d_ws, size_t ws_size,
                              hipStream_t stream) {
    const float* ff = (const float*)d_in[0];      // (B, T, N)
    const float* rec = (const float*)d_in[1];     // (2, B, N)
    const float* Wab_T = (const float*)d_in[2];   // (N, N)
    const float* Wstp_T = (const float*)d_in[3];  // (NE, NE)
    float* out = (float*)d_out;

    char* p = (char*)d_ws;
    auto alloc = [&](size_t bytes) {
        char* r = p;
        p += (bytes + 255) & ~(size_t)255;
        return r;
    };
    uint64_t* bitT = (uint64_t*)alloc((size_t)NN * 160 * 8);      // 13.1 MB
    uint32_t* Arec = (uint32_t*)alloc((size_t)AREC_U32 * 4);      // 10.5 MB
    uint32_t* Brec = (uint32_t*)alloc((size_t)BREC_U32 * 4);      // 2.6 MB
    float* hp = (float*)alloc((size_t)10 * BB * NN * 4);          // 6.55 MB
    float* rates0 = (float*)alloc((size_t)NN * BB * 4);
    float* rates1 = (float*)alloc((size_t)NN * BB * 4);
    float* u = (float*)alloc((size_t)NE * BB * 4);
    float* x = (float*)alloc((size_t)NE * BB * 4);
    float* rec0 = (float*)alloc((size_t)NN * BB * 4);
    float* rec1 = (float*)alloc((size_t)NN * BB * 4);
    ushort* Fr0 = (ushort*)alloc((size_t)320 * 512 * 2);          // 328 KB
    ushort* Fr1 = (ushort*)alloc((size_t)320 * 512 * 2);
    ushort* Fa0 = (ushort*)alloc((size_t)256 * 512 * 2);          // 262 KB
    ushort* Fa1 = (ushort*)alloc((size_t)256 * 512 * 2);

    ballot_wab<<<NN / 4, 256, 0, stream>>>(Wab_T, bitT);
    ballot_stp<<<NE / 4, 256, 0, stream>>>(Wstp_T, bitT);
    build_rec<<<(AREC_U32 + BREC_U32) / 256, 256, 0, stream>>>((const uint32_t*)bitT,
                                                               Arec, Brec);
    init_state<<<(BB * NN + 255) / 256, 256, 0, stream>>>(ff, rec, rates0, rec0, rec1, u,
                                                          x, Fr0, Fa0);
    float* rbuf[2] = {rates0, rates1};
    ushort* Frb[2] = {Fr0, Fr1};
    ushort* Fab[2] = {Fa0, Fa1};
    for (int t = 0; t < TT; ++t) {
        gemm_step<<<1600, 256, 0, stream>>>(Frb[t & 1], Fab[t & 1], Arec, Brec, hp);
        update_step<<<BB * NN / 256, 256, 0, stream>>>(ff, t, hp, rbuf[t & 1],
                                                       rbuf[(t + 1) & 1], u, x,
                                                       Frb[(t + 1) & 1], Fab[(t + 1) & 1],
                                                       rec0, rec1, out);
    }
}